// Round 1
// baseline (6979.913 us; speedup 1.0000x reference)
//
#include <hip/hip_runtime.h>
#include <math.h>

// ---- static problem config (matches reference) ----
namespace {
constexpr int N  = 102400;   // nodes
constexpr int E  = 819200;   // edges
constexpr int B_ = 16;       // graphs
constexpr int G  = 72;       // voxel cells per graph (8 x 9)
constexpr int GX = 8;
}

// ---------------- degree count + reciprocal ----------------
__global__ __launch_bounds__(256) void count_kernel(const int* __restrict__ ei,
                                                    int* __restrict__ cnt) {
  int e = blockIdx.x * 256 + threadIdx.x;
  if (e < E) atomicAdd(&cnt[ei[E + e]], 1);
}

__global__ __launch_bounds__(256) void rcnt_kernel(const int* __restrict__ cnt,
                                                   float* __restrict__ rcnt) {
  int n = blockIdx.x * 256 + threadIdx.x;
  if (n < N) rcnt[n] = 1.0f / (float)max(cnt[n], 1);
}

// ---------------- edge conv: scatter basis-weighted x@W into Y[dst] ----------------
template <int CIN, int COUT>
__global__ __launch_bounds__(256) void edge_conv(const float* __restrict__ X,
                                                 const float* __restrict__ W,
                                                 const int* __restrict__ ei,
                                                 const float* __restrict__ ea,
                                                 float* __restrict__ Y) {
  __shared__ float sW[8 * CIN * COUT];
  for (int i = threadIdx.x; i < 8 * CIN * COUT; i += 256) sW[i] = W[i];
  __syncthreads();

  int e = blockIdx.x * 256 + threadIdx.x;
  if (e >= E) return;
  int src = ei[e];
  int dst = ei[E + e];

  float u0 = fminf(fmaxf(ea[3 * e + 0], 0.f), 1.f);
  float u1 = fminf(fmaxf(ea[3 * e + 1], 0.f), 1.f);
  float u2 = fminf(fmaxf(ea[3 * e + 2], 0.f), 1.f);
  float p0 = 1.f - u0, p1 = 1.f - u1, p2 = 1.f - u2;
  // k = k0 + 2*k1 + 4*k2 ; per-dim basis [1-u, u]
  float b[8] = {p0 * p1 * p2, u0 * p1 * p2, p0 * u1 * p2, u0 * u1 * p2,
                p0 * p1 * u2, u0 * p1 * u2, p0 * u1 * u2, u0 * u1 * u2};

  float xj[CIN];
  if (CIN == 1) {
    xj[0] = X[src];
  } else {
    const float4* xp = reinterpret_cast<const float4*>(X + (size_t)src * CIN);
#pragma unroll
    for (int i = 0; i < CIN / 4; i++) {
      float4 v = xp[i];
      xj[4 * i + 0] = v.x;
      xj[4 * i + 1] = v.y;
      xj[4 * i + 2] = v.z;
      xj[4 * i + 3] = v.w;
    }
  }

  float acc[COUT];
#pragma unroll
  for (int co = 0; co < COUT; co++) acc[co] = 0.f;

#pragma unroll
  for (int k = 0; k < 8; k++) {
    float bk = b[k];
#pragma unroll
    for (int ci = 0; ci < CIN; ci++) {
      float t = bk * xj[ci];
      const float* wr = &sW[(k * CIN + ci) * COUT];
#pragma unroll
      for (int co = 0; co < COUT; co++) acc[co] += t * wr[co];
    }
  }

  float* yr = Y + (size_t)dst * COUT;
#pragma unroll
  for (int co = 0; co < COUT; co++) atomicAdd(&yr[co], acc[co]);
}

// ---------------- node op: mean + ELU (+ residual) ----------------
template <int C, bool RES>
__global__ __launch_bounds__(256) void node_act(float* __restrict__ Y,
                                                const float* __restrict__ rcnt,
                                                const float* __restrict__ res) {
  int i = blockIdx.x * 256 + threadIdx.x;
  if (i >= N * C) return;
  int n = i / C;  // C is a power of two -> shift
  float v = Y[i] * rcnt[n];
  v = v > 0.f ? v : expm1f(v);
  if (RES) v += res[i];
  Y[i] = v;
}

// ---------------- voxel-grid max pooling ----------------
__device__ __forceinline__ void atomicMaxFloat(float* addr, float val) {
  if (val >= 0.f)
    atomicMax(reinterpret_cast<int*>(addr), __float_as_int(val));
  else
    atomicMin(reinterpret_cast<unsigned int*>(addr), __float_as_uint(val));
}

__global__ __launch_bounds__(256) void pool_kernel(const float* __restrict__ h,
                                                   const float* __restrict__ pos,
                                                   const int* __restrict__ batch,
                                                   float* __restrict__ pooled) {
  int i = blockIdx.x * 256 + threadIdx.x;  // n*32 + c
  if (i >= N * 32) return;
  int n = i >> 5;
  int c = i & 31;
  int cx = (int)floorf(pos[n * 3 + 0] / 16.0f);
  int cy = (int)floorf(pos[n * 3 + 1] / 12.0f);
  int cl = batch[n] * G + cy * GX + cx;
  atomicMaxFloat(&pooled[cl * 32 + c], h[i]);
}

// ---------------- final FC: (B, G*32) @ (G*32, 2) ----------------
__global__ __launch_bounds__(256) void fc_kernel(const float* __restrict__ pooled,
                                                 const float* __restrict__ fcw,
                                                 float* __restrict__ out) {
  int b = blockIdx.x >> 1;
  int o = blockIdx.x & 1;
  const float* pb = pooled + b * (G * 32);
  float s = 0.f;
  for (int i = threadIdx.x; i < G * 32; i += 256) {
    float v = pb[i];
    v = isfinite(v) ? v : 0.f;  // empty cells (memset -NaN sentinel) -> 0
    s += v * fcw[i * 2 + o];
  }
  __shared__ float red[256];
  red[threadIdx.x] = s;
  __syncthreads();
  for (int st = 128; st > 0; st >>= 1) {
    if (threadIdx.x < st) red[threadIdx.x] += red[threadIdx.x + st];
    __syncthreads();
  }
  if (threadIdx.x == 0) out[b * 2 + o] = red[0];
}

extern "C" void kernel_launch(void* const* d_in, const int* in_sizes, int n_in,
                              void* d_out, int out_size, void* d_ws, size_t ws_size,
                              hipStream_t stream) {
  const float* x     = (const float*)d_in[0];
  const float* pos   = (const float*)d_in[1];
  const float* ea    = (const float*)d_in[2];
  const int*   ei    = (const int*)d_in[3];
  const int*   batch = (const int*)d_in[4];
  const float* fcw   = (const float*)d_in[5];
  const float* w1    = (const float*)d_in[6];
  const float* w2    = (const float*)d_in[7];
  const float* w3    = (const float*)d_in[8];
  const float* w4    = (const float*)d_in[9];
  const float* w5    = (const float*)d_in[10];
  const float* w6    = (const float*)d_in[11];
  const float* w7    = (const float*)d_in[12];
  float* out = (float*)d_out;

  char* ws = (char*)d_ws;
  float* rcnt   = (float*)ws;                      // N floats
  int*   cnt    = (int*)(ws + (size_t)N * 4);      // N ints
  float* bufA   = (float*)(ws + (size_t)N * 8);    // N*32 floats
  float* bufB   = bufA + (size_t)N * 32;           // N*32 floats
  float* bufC   = bufB + (size_t)N * 32;           // N*32 floats
  float* pooled = bufC + (size_t)N * 32;           // B*G*32 floats

  const int EB = E / 256;  // 3200

  hipMemsetAsync(cnt, 0, (size_t)N * 4, stream);
  count_kernel<<<EB, 256, 0, stream>>>(ei, cnt);
  rcnt_kernel<<<N / 256, 256, 0, stream>>>(cnt, rcnt);

  // conv1: 1 -> 8   (x -> bufA)
  hipMemsetAsync(bufA, 0, (size_t)N * 8 * 4, stream);
  edge_conv<1, 8><<<EB, 256, 0, stream>>>(x, w1, ei, ea, bufA);
  node_act<8, false><<<N * 8 / 256, 256, 0, stream>>>(bufA, rcnt, nullptr);

  // conv2: 8 -> 16  (bufA -> bufB)  [bufB becomes h_sc]
  hipMemsetAsync(bufB, 0, (size_t)N * 16 * 4, stream);
  edge_conv<8, 16><<<EB, 256, 0, stream>>>(bufA, w2, ei, ea, bufB);
  node_act<16, false><<<N * 16 / 256, 256, 0, stream>>>(bufB, rcnt, nullptr);

  // conv3: 16 -> 16 (bufB -> bufC)
  hipMemsetAsync(bufC, 0, (size_t)N * 16 * 4, stream);
  edge_conv<16, 16><<<EB, 256, 0, stream>>>(bufB, w3, ei, ea, bufC);
  node_act<16, false><<<N * 16 / 256, 256, 0, stream>>>(bufC, rcnt, nullptr);

  // conv4: 16 -> 16 (bufC -> bufA) + residual bufB
  hipMemsetAsync(bufA, 0, (size_t)N * 16 * 4, stream);
  edge_conv<16, 16><<<EB, 256, 0, stream>>>(bufC, w4, ei, ea, bufA);
  node_act<16, true><<<N * 16 / 256, 256, 0, stream>>>(bufA, rcnt, bufB);

  // conv5: 16 -> 32 (bufA -> bufB)  [bufB becomes h_sc2]
  hipMemsetAsync(bufB, 0, (size_t)N * 32 * 4, stream);
  edge_conv<16, 32><<<EB, 256, 0, stream>>>(bufA, w5, ei, ea, bufB);
  node_act<32, false><<<N * 32 / 256, 256, 0, stream>>>(bufB, rcnt, nullptr);

  // conv6: 32 -> 32 (bufB -> bufC)
  hipMemsetAsync(bufC, 0, (size_t)N * 32 * 4, stream);
  edge_conv<32, 32><<<EB, 256, 0, stream>>>(bufB, w6, ei, ea, bufC);
  node_act<32, false><<<N * 32 / 256, 256, 0, stream>>>(bufC, rcnt, nullptr);

  // conv7: 32 -> 32 (bufC -> bufA) + residual bufB
  hipMemsetAsync(bufA, 0, (size_t)N * 32 * 4, stream);
  edge_conv<32, 32><<<EB, 256, 0, stream>>>(bufC, w7, ei, ea, bufA);
  node_act<32, true><<<N * 32 / 256, 256, 0, stream>>>(bufA, rcnt, bufB);

  // voxel max pool: init pooled to 0xFF bytes (-NaN sentinel), atomic-max, FC
  hipMemsetAsync(pooled, 0xFF, (size_t)B_ * G * 32 * 4, stream);
  pool_kernel<<<N * 32 / 256, 256, 0, stream>>>(bufA, pos, batch, pooled);
  fc_kernel<<<B_ * 2, 256, 0, stream>>>(pooled, fcw, out);
}

// Round 2
// 2939.822 us; speedup vs baseline: 2.3743x; 2.3743x over previous
//
#include <hip/hip_runtime.h>
#include <math.h>

// ---- static problem config (matches reference) ----
namespace {
constexpr int N  = 102400;   // nodes
constexpr int E  = 819200;   // edges
constexpr int B_ = 16;       // graphs
constexpr int G  = 72;       // voxel cells per graph (8 x 9)
constexpr int GX = 8;
constexpr int NB = N / 256;  // 400 blocks over nodes
constexpr int EB = E / 256;  // 3200 blocks over edges
}

// ================= CSR build =================

__global__ __launch_bounds__(256) void count_kernel(const int* __restrict__ ei,
                                                    int* __restrict__ cnt) {
  int e = blockIdx.x * 256 + threadIdx.x;
  atomicAdd(&cnt[ei[E + e]], 1);
}

__global__ __launch_bounds__(256) void rcnt_kernel(const int* __restrict__ cnt,
                                                   float* __restrict__ rcnt) {
  int n = blockIdx.x * 256 + threadIdx.x;
  rcnt[n] = 1.0f / (float)max(cnt[n], 1);
}

// per-256-chunk sums of cnt
__global__ __launch_bounds__(256) void reduce_cnt(const int* __restrict__ cnt,
                                                  int* __restrict__ bsum) {
  __shared__ int s[256];
  int i = blockIdx.x * 256 + threadIdx.x;
  s[threadIdx.x] = cnt[i];
  __syncthreads();
  for (int st = 128; st > 0; st >>= 1) {
    if (threadIdx.x < st) s[threadIdx.x] += s[threadIdx.x + st];
    __syncthreads();
  }
  if (threadIdx.x == 0) bsum[blockIdx.x] = s[0];
}

// single-block exclusive scan of the NB block sums
__global__ __launch_bounds__(512) void scan_bsum(const int* __restrict__ bsum,
                                                 int* __restrict__ boff) {
  __shared__ int s[512];
  int i = threadIdx.x;
  int v = (i < NB) ? bsum[i] : 0;
  s[i] = v;
  __syncthreads();
  for (int st = 1; st < 512; st <<= 1) {
    int t = (i >= st) ? s[i - st] : 0;
    __syncthreads();
    s[i] += t;
    __syncthreads();
  }
  if (i < NB) boff[i] = s[i] - v;  // exclusive
}

// rowptr[n] = exclusive scan of cnt; cursor starts equal to rowptr
__global__ __launch_bounds__(256) void write_rowptr(const int* __restrict__ cnt,
                                                    const int* __restrict__ boff,
                                                    int* __restrict__ rowptr,
                                                    int* __restrict__ cursor) {
  __shared__ int s[256];
  int i = blockIdx.x * 256 + threadIdx.x;
  int v = cnt[i];
  s[threadIdx.x] = v;
  __syncthreads();
  for (int st = 1; st < 256; st <<= 1) {
    int t = (threadIdx.x >= st) ? s[threadIdx.x - st] : 0;
    __syncthreads();
    s[threadIdx.x] += t;
    __syncthreads();
  }
  int off = boff[blockIdx.x] + s[threadIdx.x] - v;  // exclusive
  rowptr[i] = off;
  cursor[i] = off;
  if (i == N - 1) rowptr[N] = off + v;
}

// scatter edge records (src + clamped pseudo-coords) into CSR order
__global__ __launch_bounds__(256) void edge_scatter(const int* __restrict__ ei,
                                                    const float* __restrict__ ea,
                                                    int* __restrict__ cursor,
                                                    float4* __restrict__ rec) {
  int e = blockIdx.x * 256 + threadIdx.x;
  int src = ei[e];
  int dst = ei[E + e];
  float u0 = fminf(fmaxf(ea[3 * e + 0], 0.f), 1.f);
  float u1 = fminf(fmaxf(ea[3 * e + 1], 0.f), 1.f);
  float u2 = fminf(fmaxf(ea[3 * e + 2], 0.f), 1.f);
  int slot = atomicAdd(&cursor[dst], 1);
  rec[slot] = make_float4(__int_as_float(src), u0, u1, u2);
}

// ============ bucket-sort nodes by degree (uniform wave trip counts) ============

__global__ __launch_bounds__(256) void hist_kernel(const int* __restrict__ cnt,
                                                   int* __restrict__ hist) {
  int n = blockIdx.x * 256 + threadIdx.x;
  atomicAdd(&hist[min(cnt[n], 63)], 1);
}

__global__ __launch_bounds__(64) void hist_scan(int* __restrict__ hist) {
  __shared__ int s[64];
  int i = threadIdx.x;
  int v = hist[i];
  s[i] = v;
  __syncthreads();
  for (int st = 1; st < 64; st <<= 1) {
    int t = (i >= st) ? s[i - st] : 0;
    __syncthreads();
    s[i] += t;
    __syncthreads();
  }
  hist[i] = s[i] - v;  // exclusive -> becomes cursor
}

__global__ __launch_bounds__(256) void order_kernel(const int* __restrict__ cnt,
                                                    int* __restrict__ hcur,
                                                    int* __restrict__ order) {
  int n = blockIdx.x * 256 + threadIdx.x;
  int pos = atomicAdd(&hcur[min(cnt[n], 63)], 1);
  order[pos] = n;
}

// ================= pooling helper =================
__device__ __forceinline__ void atomicMaxFloat(float* addr, float val) {
  if (val >= 0.f)
    atomicMax(reinterpret_cast<int*>(addr), __float_as_int(val));
  else
    atomicMin(reinterpret_cast<unsigned int*>(addr), __float_as_uint(val));
}

// ================= gather-based spline conv =================
// one thread per dst node; mean + ELU (+ residual) fused in epilogue.
// W read with wave-uniform constant-offset indices -> scalar loads (SMEM pipe).
template <int CIN, int COUT, bool RES, bool POOL>
__global__ __launch_bounds__(256) void node_conv(
    const float* __restrict__ X, const float* __restrict__ W,
    const float4* __restrict__ rec, const int* __restrict__ rowptr,
    const int* __restrict__ order, const float* __restrict__ rcnt,
    const float* __restrict__ res, float* __restrict__ Y,
    const float* __restrict__ pos, const int* __restrict__ batch,
    float* __restrict__ pooled) {
  int t = blockIdx.x * 256 + threadIdx.x;
  int n = order[t];
  int beg = rowptr[n], end = rowptr[n + 1];

  float acc[COUT];
#pragma unroll
  for (int co = 0; co < COUT; co++) acc[co] = 0.f;

  for (int e = beg; e < end; e++) {
    float4 r = rec[e];
    int src = __float_as_int(r.x);
    float u0 = r.y, u1 = r.z, u2 = r.w;

    float xj[CIN];
    if (CIN == 1) {
      xj[0] = X[src];
    } else {
      const float4* xp = reinterpret_cast<const float4*>(X + (size_t)src * CIN);
#pragma unroll
      for (int i = 0; i < CIN / 4; i++) {
        float4 v = xp[i];
        xj[4 * i + 0] = v.x;
        xj[4 * i + 1] = v.y;
        xj[4 * i + 2] = v.z;
        xj[4 * i + 3] = v.w;
      }
    }

    // k loop kept runtime (wave-uniform) to bound code size; bk via selects
    for (int k = 0; k < 8; k++) {
      float bk = ((k & 1) ? u0 : 1.f - u0) * ((k & 2) ? u1 : 1.f - u1) *
                 ((k & 4) ? u2 : 1.f - u2);
      const float* wk = W + k * CIN * COUT;  // wave-uniform base
#pragma unroll
      for (int ci = 0; ci < CIN; ci++) {
        float tt = bk * xj[ci];
#pragma unroll
        for (int co = 0; co < COUT; co++)
          acc[co] = fmaf(tt, wk[ci * COUT + co], acc[co]);
      }
    }
  }

  float rc = rcnt[n];
  float v[COUT];
#pragma unroll
  for (int co = 0; co < COUT; co++) {
    float w = acc[co] * rc;
    w = w > 0.f ? w : expm1f(w);
    if (RES) w += res[(size_t)n * COUT + co];
    v[co] = w;
  }

  if (POOL) {
    int cx = (int)floorf(pos[n * 3 + 0] / 16.0f);
    int cy = (int)floorf(pos[n * 3 + 1] / 12.0f);
    int cl = batch[n] * G + cy * GX + cx;
    float* pr = pooled + cl * 32;
#pragma unroll
    for (int co = 0; co < COUT; co++) atomicMaxFloat(&pr[co], v[co]);
  } else {
    float4* yp = reinterpret_cast<float4*>(Y + (size_t)n * COUT);
#pragma unroll
    for (int i = 0; i < COUT / 4; i++)
      yp[i] = make_float4(v[4 * i], v[4 * i + 1], v[4 * i + 2], v[4 * i + 3]);
  }
}

// ================= final FC =================
__global__ __launch_bounds__(256) void fc_kernel(const float* __restrict__ pooled,
                                                 const float* __restrict__ fcw,
                                                 float* __restrict__ out) {
  int b = blockIdx.x >> 1;
  int o = blockIdx.x & 1;
  const float* pb = pooled + b * (G * 32);
  float s = 0.f;
  for (int i = threadIdx.x; i < G * 32; i += 256) {
    float v = pb[i];
    v = isfinite(v) ? v : 0.f;  // untouched cells (0xFF memset -> NaN) -> 0
    s += v * fcw[i * 2 + o];
  }
  __shared__ float red[256];
  red[threadIdx.x] = s;
  __syncthreads();
  for (int st = 128; st > 0; st >>= 1) {
    if (threadIdx.x < st) red[threadIdx.x] += red[threadIdx.x + st];
    __syncthreads();
  }
  if (threadIdx.x == 0) out[b * 2 + o] = red[0];
}

extern "C" void kernel_launch(void* const* d_in, const int* in_sizes, int n_in,
                              void* d_out, int out_size, void* d_ws, size_t ws_size,
                              hipStream_t stream) {
  const float* x     = (const float*)d_in[0];
  const float* pos   = (const float*)d_in[1];
  const float* ea    = (const float*)d_in[2];
  const int*   ei    = (const int*)d_in[3];
  const int*   batch = (const int*)d_in[4];
  const float* fcw   = (const float*)d_in[5];
  const float* w1    = (const float*)d_in[6];
  const float* w2    = (const float*)d_in[7];
  const float* w3    = (const float*)d_in[8];
  const float* w4    = (const float*)d_in[9];
  const float* w5    = (const float*)d_in[10];
  const float* w6    = (const float*)d_in[11];
  const float* w7    = (const float*)d_in[12];
  float* out = (float*)d_out;

  // ---- workspace layout (256B-aligned chunks) ----
  char* ws = (char*)d_ws;
  size_t off = 0;
  auto alloc = [&](size_t bytes) {
    size_t p = off;
    off += (bytes + 255) & ~(size_t)255;
    return ws + p;
  };
  float*  rcnt   = (float*)alloc((size_t)N * 4);
  int*    cnt    = (int*)alloc((size_t)N * 4);
  int*    rowptr = (int*)alloc((size_t)(N + 1) * 4);
  int*    cursor = (int*)alloc((size_t)N * 4);
  int*    bsum   = (int*)alloc(512 * 4);
  int*    boff   = (int*)alloc(512 * 4);
  int*    hist   = (int*)alloc(64 * 4);
  int*    order  = (int*)alloc((size_t)N * 4);
  float4* rec    = (float4*)alloc((size_t)E * 16);
  float*  bufA   = (float*)alloc((size_t)N * 32 * 4);
  float*  bufB   = (float*)alloc((size_t)N * 32 * 4);
  float*  bufC   = (float*)alloc((size_t)N * 32 * 4);
  float*  pooled = (float*)alloc((size_t)B_ * G * 32 * 4);

  // ---- CSR build ----
  hipMemsetAsync(cnt, 0, (size_t)N * 4, stream);
  count_kernel<<<EB, 256, 0, stream>>>(ei, cnt);
  rcnt_kernel<<<NB, 256, 0, stream>>>(cnt, rcnt);
  reduce_cnt<<<NB, 256, 0, stream>>>(cnt, bsum);
  scan_bsum<<<1, 512, 0, stream>>>(bsum, boff);
  write_rowptr<<<NB, 256, 0, stream>>>(cnt, boff, rowptr, cursor);
  edge_scatter<<<EB, 256, 0, stream>>>(ei, ea, cursor, rec);

  // ---- degree bucket sort ----
  hipMemsetAsync(hist, 0, 64 * 4, stream);
  hist_kernel<<<NB, 256, 0, stream>>>(cnt, hist);
  hist_scan<<<1, 64, 0, stream>>>(hist);
  order_kernel<<<NB, 256, 0, stream>>>(cnt, hist, order);

  // ---- pooled init (must precede conv7) ----
  hipMemsetAsync(pooled, 0xFF, (size_t)B_ * G * 32 * 4, stream);

  // ---- conv ladder ----
  // conv1: 1->8    x -> A
  node_conv<1, 8, false, false><<<NB, 256, 0, stream>>>(
      x, w1, rec, rowptr, order, rcnt, nullptr, bufA, nullptr, nullptr, nullptr);
  // conv2: 8->16   A -> B   (B = h_sc1)
  node_conv<8, 16, false, false><<<NB, 256, 0, stream>>>(
      bufA, w2, rec, rowptr, order, rcnt, nullptr, bufB, nullptr, nullptr, nullptr);
  // conv3: 16->16  B -> C
  node_conv<16, 16, false, false><<<NB, 256, 0, stream>>>(
      bufB, w3, rec, rowptr, order, rcnt, nullptr, bufC, nullptr, nullptr, nullptr);
  // conv4: 16->16  C -> A, + residual B
  node_conv<16, 16, true, false><<<NB, 256, 0, stream>>>(
      bufC, w4, rec, rowptr, order, rcnt, bufB, bufA, nullptr, nullptr, nullptr);
  // conv5: 16->32  A -> C   (C = h_sc2)
  node_conv<16, 32, false, false><<<NB, 256, 0, stream>>>(
      bufA, w5, rec, rowptr, order, rcnt, nullptr, bufC, nullptr, nullptr, nullptr);
  // conv6: 32->32  C -> B
  node_conv<32, 32, false, false><<<NB, 256, 0, stream>>>(
      bufC, w6, rec, rowptr, order, rcnt, nullptr, bufB, nullptr, nullptr, nullptr);
  // conv7: 32->32  B -> (pool), + residual C
  node_conv<32, 32, true, true><<<NB, 256, 0, stream>>>(
      bufB, w7, rec, rowptr, order, rcnt, bufC, nullptr, pos, batch, pooled);

  // ---- FC ----
  fc_kernel<<<B_ * 2, 256, 0, stream>>>(pooled, fcw, out);
}

// Round 3
// 1803.872 us; speedup vs baseline: 3.8694x; 1.6297x over previous
//
#include <hip/hip_runtime.h>
#include <math.h>

// ---- static problem config (matches reference) ----
namespace {
constexpr int N  = 102400;   // nodes
constexpr int E  = 819200;   // edges
constexpr int B_ = 16;       // graphs
constexpr int G  = 72;       // voxel cells per graph (8 x 9)
constexpr int GX = 8;
constexpr int NB = N / 256;  // 400 blocks over nodes
constexpr int EB = E / 256;  // 3200 blocks over edges
}

// ================= CSR build =================

__global__ __launch_bounds__(256) void count_kernel(const int* __restrict__ ei,
                                                    int* __restrict__ cnt) {
  int e = blockIdx.x * 256 + threadIdx.x;
  atomicAdd(&cnt[ei[E + e]], 1);
}

__global__ __launch_bounds__(256) void rcnt_kernel(const int* __restrict__ cnt,
                                                   float* __restrict__ rcnt) {
  int n = blockIdx.x * 256 + threadIdx.x;
  rcnt[n] = 1.0f / (float)max(cnt[n], 1);
}

// per-256-chunk sums of cnt
__global__ __launch_bounds__(256) void reduce_cnt(const int* __restrict__ cnt,
                                                  int* __restrict__ bsum) {
  __shared__ int s[256];
  int i = blockIdx.x * 256 + threadIdx.x;
  s[threadIdx.x] = cnt[i];
  __syncthreads();
  for (int st = 128; st > 0; st >>= 1) {
    if (threadIdx.x < st) s[threadIdx.x] += s[threadIdx.x + st];
    __syncthreads();
  }
  if (threadIdx.x == 0) bsum[blockIdx.x] = s[0];
}

// single-block exclusive scan of the NB block sums
__global__ __launch_bounds__(512) void scan_bsum(const int* __restrict__ bsum,
                                                 int* __restrict__ boff) {
  __shared__ int s[512];
  int i = threadIdx.x;
  int v = (i < NB) ? bsum[i] : 0;
  s[i] = v;
  __syncthreads();
  for (int st = 1; st < 512; st <<= 1) {
    int t = (i >= st) ? s[i - st] : 0;
    __syncthreads();
    s[i] += t;
    __syncthreads();
  }
  if (i < NB) boff[i] = s[i] - v;  // exclusive
}

// rowptr[n] = exclusive scan of cnt; cursor starts equal to rowptr
__global__ __launch_bounds__(256) void write_rowptr(const int* __restrict__ cnt,
                                                    const int* __restrict__ boff,
                                                    int* __restrict__ rowptr,
                                                    int* __restrict__ cursor) {
  __shared__ int s[256];
  int i = blockIdx.x * 256 + threadIdx.x;
  int v = cnt[i];
  s[threadIdx.x] = v;
  __syncthreads();
  for (int st = 1; st < 256; st <<= 1) {
    int t = (threadIdx.x >= st) ? s[threadIdx.x - st] : 0;
    __syncthreads();
    s[threadIdx.x] += t;
    __syncthreads();
  }
  int off = boff[blockIdx.x] + s[threadIdx.x] - v;  // exclusive
  rowptr[i] = off;
  cursor[i] = off;
  if (i == N - 1) rowptr[N] = off + v;
}

// scatter edge records (src + clamped pseudo-coords) into CSR order
__global__ __launch_bounds__(256) void edge_scatter(const int* __restrict__ ei,
                                                    const float* __restrict__ ea,
                                                    int* __restrict__ cursor,
                                                    float4* __restrict__ rec) {
  int e = blockIdx.x * 256 + threadIdx.x;
  int src = ei[e];
  int dst = ei[E + e];
  float u0 = fminf(fmaxf(ea[3 * e + 0], 0.f), 1.f);
  float u1 = fminf(fmaxf(ea[3 * e + 1], 0.f), 1.f);
  float u2 = fminf(fmaxf(ea[3 * e + 2], 0.f), 1.f);
  int slot = atomicAdd(&cursor[dst], 1);
  rec[slot] = make_float4(__int_as_float(src), u0, u1, u2);
}

// ============ bucket-sort nodes by degree (uniform wave trip counts) ============

__global__ __launch_bounds__(256) void hist_kernel(const int* __restrict__ cnt,
                                                   int* __restrict__ hist) {
  int n = blockIdx.x * 256 + threadIdx.x;
  atomicAdd(&hist[min(cnt[n], 63)], 1);
}

__global__ __launch_bounds__(64) void hist_scan(int* __restrict__ hist) {
  __shared__ int s[64];
  int i = threadIdx.x;
  int v = hist[i];
  s[i] = v;
  __syncthreads();
  for (int st = 1; st < 64; st <<= 1) {
    int t = (i >= st) ? s[i - st] : 0;
    __syncthreads();
    s[i] += t;
    __syncthreads();
  }
  hist[i] = s[i] - v;  // exclusive -> becomes cursor
}

__global__ __launch_bounds__(256) void order_kernel(const int* __restrict__ cnt,
                                                    int* __restrict__ hcur,
                                                    int* __restrict__ order) {
  int n = blockIdx.x * 256 + threadIdx.x;
  int pos = atomicAdd(&hcur[min(cnt[n], 63)], 1);
  order[pos] = n;
}

// ================= pooling helper =================
__device__ __forceinline__ void atomicMaxFloat(float* addr, float val) {
  if (val >= 0.f)
    atomicMax(reinterpret_cast<int*>(addr), __float_as_int(val));
  else
    atomicMin(reinterpret_cast<unsigned int*>(addr), __float_as_uint(val));
}

// ================= edge-parallel gather spline conv =================
// 8 lanes per dst node, one edge per lane; full acc[COUT] per lane;
// 3-round shfl_xor butterfly; lane extracts its COUT/8 slice (unrolled
// select chain -> no dynamic register indexing); fused mean+ELU+residual
// epilogue with coalesced slice store (or voxel-pool atomics).
template <int CIN, int COUT, bool RES, bool POOL>
__global__ __launch_bounds__(256) void node_conv_ep(
    const float* __restrict__ X, const float* __restrict__ W,
    const float4* __restrict__ rec, const int* __restrict__ rowptr,
    const int* __restrict__ order, const float* __restrict__ rcnt,
    const float* __restrict__ res, float* __restrict__ Y,
    const float* __restrict__ pos, const int* __restrict__ batch,
    float* __restrict__ pooled) {
  int t = blockIdx.x * 256 + threadIdx.x;
  int slot = t >> 3;   // node slot (8 lanes each, contiguous in wave)
  int l = t & 7;       // lane within node
  int n = order[slot];
  int beg = rowptr[n], end = rowptr[n + 1];

  float acc[COUT];
#pragma unroll
  for (int co = 0; co < COUT; co++) acc[co] = 0.f;

  for (int e = beg + l; e < end; e += 8) {
    float4 r = rec[e];
    int src = __float_as_int(r.x);
    float u0 = r.y, u1 = r.z, u2 = r.w;

    float xj[CIN];
    if (CIN == 1) {
      xj[0] = X[src];
    } else {
      const float4* xp = reinterpret_cast<const float4*>(X + (size_t)src * CIN);
#pragma unroll
      for (int i = 0; i < CIN / 4; i++) {
        float4 v = xp[i];
        xj[4 * i + 0] = v.x;
        xj[4 * i + 1] = v.y;
        xj[4 * i + 2] = v.z;
        xj[4 * i + 3] = v.w;
      }
    }

    // runtime (wave-uniform) k loop keeps code size in I$; W via s_loads
    for (int k = 0; k < 8; k++) {
      float bk = ((k & 1) ? u0 : 1.f - u0) * ((k & 2) ? u1 : 1.f - u1) *
                 ((k & 4) ? u2 : 1.f - u2);
      const float* wk = W + k * CIN * COUT;
#pragma unroll
      for (int ci = 0; ci < CIN; ci++) {
        float tt = bk * xj[ci];
#pragma unroll
        for (int co = 0; co < COUT; co++)
          acc[co] = fmaf(tt, wk[ci * COUT + co], acc[co]);
      }
    }
  }

  // butterfly reduce across the 8 lanes of this node
#pragma unroll
  for (int m = 1; m < 8; m <<= 1) {
#pragma unroll
    for (int co = 0; co < COUT; co++) acc[co] += __shfl_xor(acc[co], m, 64);
  }

  // extract my slice with compile-time indices (no dynamic reg indexing)
  constexpr int CPL = COUT / 8;
  float mv[CPL];
#pragma unroll
  for (int g = 0; g < 8; g++) {
    if (l == g) {
#pragma unroll
      for (int i = 0; i < CPL; i++) mv[i] = acc[g * CPL + i];
    }
  }

  float rc = rcnt[n];
#pragma unroll
  for (int i = 0; i < CPL; i++) {
    float w = mv[i] * rc;
    w = w > 0.f ? w : expm1f(w);
    if (RES) w += res[(size_t)n * COUT + l * CPL + i];
    mv[i] = w;
  }

  if (POOL) {
    int cx = (int)floorf(pos[n * 3 + 0] / 16.0f);
    int cy = (int)floorf(pos[n * 3 + 1] / 12.0f);
    int cl = batch[n] * G + cy * GX + cx;
    float* pr = pooled + cl * 32 + l * CPL;
#pragma unroll
    for (int i = 0; i < CPL; i++) atomicMaxFloat(&pr[i], mv[i]);
  } else {
    float* yp = Y + (size_t)n * COUT + l * CPL;
    if (CPL == 4) {
      *reinterpret_cast<float4*>(yp) = make_float4(mv[0], mv[1], mv[2], mv[3]);
    } else if (CPL == 2) {
      *reinterpret_cast<float2*>(yp) = make_float2(mv[0], mv[1]);
    } else {
      yp[0] = mv[0];
    }
  }
}

// ================= final FC =================
__global__ __launch_bounds__(256) void fc_kernel(const float* __restrict__ pooled,
                                                 const float* __restrict__ fcw,
                                                 float* __restrict__ out) {
  int b = blockIdx.x >> 1;
  int o = blockIdx.x & 1;
  const float* pb = pooled + b * (G * 32);
  float s = 0.f;
  for (int i = threadIdx.x; i < G * 32; i += 256) {
    float v = pb[i];
    v = isfinite(v) ? v : 0.f;  // untouched cells (0xFF memset -> NaN) -> 0
    s += v * fcw[i * 2 + o];
  }
  __shared__ float red[256];
  red[threadIdx.x] = s;
  __syncthreads();
  for (int st = 128; st > 0; st >>= 1) {
    if (threadIdx.x < st) red[threadIdx.x] += red[threadIdx.x + st];
    __syncthreads();
  }
  if (threadIdx.x == 0) out[b * 2 + o] = red[0];
}

extern "C" void kernel_launch(void* const* d_in, const int* in_sizes, int n_in,
                              void* d_out, int out_size, void* d_ws, size_t ws_size,
                              hipStream_t stream) {
  const float* x     = (const float*)d_in[0];
  const float* pos   = (const float*)d_in[1];
  const float* ea    = (const float*)d_in[2];
  const int*   ei    = (const int*)d_in[3];
  const int*   batch = (const int*)d_in[4];
  const float* fcw   = (const float*)d_in[5];
  const float* w1    = (const float*)d_in[6];
  const float* w2    = (const float*)d_in[7];
  const float* w3    = (const float*)d_in[8];
  const float* w4    = (const float*)d_in[9];
  const float* w5    = (const float*)d_in[10];
  const float* w6    = (const float*)d_in[11];
  const float* w7    = (const float*)d_in[12];
  float* out = (float*)d_out;

  // ---- workspace layout (256B-aligned chunks) ----
  char* ws = (char*)d_ws;
  size_t off = 0;
  auto alloc = [&](size_t bytes) {
    size_t p = off;
    off += (bytes + 255) & ~(size_t)255;
    return ws + p;
  };
  float*  rcnt   = (float*)alloc((size_t)N * 4);
  int*    cnt    = (int*)alloc((size_t)N * 4);
  int*    rowptr = (int*)alloc((size_t)(N + 1) * 4);
  int*    cursor = (int*)alloc((size_t)N * 4);
  int*    bsum   = (int*)alloc(512 * 4);
  int*    boff   = (int*)alloc(512 * 4);
  int*    hist   = (int*)alloc(64 * 4);
  int*    order  = (int*)alloc((size_t)N * 4);
  float4* rec    = (float4*)alloc((size_t)E * 16);
  float*  bufA   = (float*)alloc((size_t)N * 32 * 4);
  float*  bufB   = (float*)alloc((size_t)N * 32 * 4);
  float*  bufC   = (float*)alloc((size_t)N * 32 * 4);
  float*  pooled = (float*)alloc((size_t)B_ * G * 32 * 4);

  const int NB8 = N * 8 / 256;  // 3200 blocks for edge-parallel convs

  // ---- CSR build ----
  hipMemsetAsync(cnt, 0, (size_t)N * 4, stream);
  count_kernel<<<EB, 256, 0, stream>>>(ei, cnt);
  rcnt_kernel<<<NB, 256, 0, stream>>>(cnt, rcnt);
  reduce_cnt<<<NB, 256, 0, stream>>>(cnt, bsum);
  scan_bsum<<<1, 512, 0, stream>>>(bsum, boff);
  write_rowptr<<<NB, 256, 0, stream>>>(cnt, boff, rowptr, cursor);
  edge_scatter<<<EB, 256, 0, stream>>>(ei, ea, cursor, rec);

  // ---- degree bucket sort ----
  hipMemsetAsync(hist, 0, 64 * 4, stream);
  hist_kernel<<<NB, 256, 0, stream>>>(cnt, hist);
  hist_scan<<<1, 64, 0, stream>>>(hist);
  order_kernel<<<NB, 256, 0, stream>>>(cnt, hist, order);

  // ---- pooled init (must precede conv7) ----
  hipMemsetAsync(pooled, 0xFF, (size_t)B_ * G * 32 * 4, stream);

  // ---- conv ladder (edge-parallel, 8 lanes/node) ----
  // conv1: 1->8    x -> A
  node_conv_ep<1, 8, false, false><<<NB8, 256, 0, stream>>>(
      x, w1, rec, rowptr, order, rcnt, nullptr, bufA, nullptr, nullptr, nullptr);
  // conv2: 8->16   A -> B   (B = h_sc1)
  node_conv_ep<8, 16, false, false><<<NB8, 256, 0, stream>>>(
      bufA, w2, rec, rowptr, order, rcnt, nullptr, bufB, nullptr, nullptr, nullptr);
  // conv3: 16->16  B -> C
  node_conv_ep<16, 16, false, false><<<NB8, 256, 0, stream>>>(
      bufB, w3, rec, rowptr, order, rcnt, nullptr, bufC, nullptr, nullptr, nullptr);
  // conv4: 16->16  C -> A, + residual B
  node_conv_ep<16, 16, true, false><<<NB8, 256, 0, stream>>>(
      bufC, w4, rec, rowptr, order, rcnt, bufB, bufA, nullptr, nullptr, nullptr);
  // conv5: 16->32  A -> C   (C = h_sc2)
  node_conv_ep<16, 32, false, false><<<NB8, 256, 0, stream>>>(
      bufA, w5, rec, rowptr, order, rcnt, nullptr, bufC, nullptr, nullptr, nullptr);
  // conv6: 32->32  C -> B
  node_conv_ep<32, 32, false, false><<<NB8, 256, 0, stream>>>(
      bufC, w6, rec, rowptr, order, rcnt, nullptr, bufB, nullptr, nullptr, nullptr);
  // conv7: 32->32  B -> (pool), + residual C
  node_conv_ep<32, 32, true, true><<<NB8, 256, 0, stream>>>(
      bufB, w7, rec, rowptr, order, rcnt, bufC, nullptr, pos, batch, pooled);

  // ---- FC ----
  fc_kernel<<<B_ * 2, 256, 0, stream>>>(pooled, fcw, out);
}